// Round 4
// baseline (3129.439 us; speedup 1.0000x reference)
//
#include <hip/hip_runtime.h>
#include <hip/hip_bf16.h>
#include <math.h>

typedef __hip_bfloat16 bf16;
typedef __attribute__((ext_vector_type(8))) short short8;
typedef __attribute__((ext_vector_type(4))) float floatx4;

#define DEV static __device__ __forceinline__

DEV float bf2f(unsigned short u) {
  union { unsigned int i; float f; } x;
  x.i = ((unsigned int)u) << 16;
  return x.f;
}
DEV unsigned short f2bf_bits(float f) {
  union { bf16 h; unsigned short u; } x;
  x.h = __float2bfloat16(f);
  return x.u;
}
DEV short8 cvt8(float4 a, float4 b) {
  short8 r;
  r[0] = (short)f2bf_bits(a.x); r[1] = (short)f2bf_bits(a.y);
  r[2] = (short)f2bf_bits(a.z); r[3] = (short)f2bf_bits(a.w);
  r[4] = (short)f2bf_bits(b.x); r[5] = (short)f2bf_bits(b.y);
  r[6] = (short)f2bf_bits(b.z); r[7] = (short)f2bf_bits(b.w);
  return r;
}

// window-gather (chunk-local): window-row -> source row (fuses roll(-4,-4)+partition)
DEV int gather_win_row(int wr) {
  int bw = wr >> 6, n = wr & 63;
  int bt = bw >> 2, w2 = bw & 3;
  int wi = w2 >> 1, wj = w2 & 1;
  int r = n >> 3, c = n & 7;
  int sr = (wi * 8 + r + 4) & 15;
  int sc = (wj * 8 + c + 4) & 15;
  return bt * 256 + sr * 16 + sc;
}

enum { BIAS_SIMPLE = 0, BIAS_QKV = 1 };
enum { ACT_NONE = 0, ACT_GELU = 1 };
enum { A_F32 = 0, A_BF16 = 1 };

// C[M,N] = act(A[M,K] @ B[N,K]^T + bias). A f32 or bf16 (ASRC), B/bias f32,
// C bf16, fp32 accum via MFMA. BM=BN=128, BK=64, 256 threads = 4 waves (2x2).
template <int ASRC, int GATHER, int BIASMODE, int ACT>
__global__ __launch_bounds__(256, 2) void gemm_bt(
    const void* __restrict__ Av, const float* __restrict__ B,
    const float* __restrict__ bias0, const float* __restrict__ bias1,
    bf16* __restrict__ C, int M, int N, int K)
{
  __shared__ __align__(16) unsigned short As[128 * 64];
  __shared__ __align__(16) unsigned short Bs[128 * 64];
  const int tid = threadIdx.x;
  const int lane = tid & 63;
  const int wave = tid >> 6;
  const int waveM = wave >> 1, waveN = wave & 1;
  const int tileM = blockIdx.x * 128, tileN = blockIdx.y * 128;

  const int row0 = tid >> 3;          // 0..31
  const int kOff = (tid & 7) * 8;     // 0..56

  size_t aoff[4], boff[4];
#pragma unroll
  for (int t = 0; t < 4; ++t) {
    int gr = tileM + row0 + 32 * t;
    int sr = GATHER ? gather_win_row(gr) : gr;
    aoff[t] = (size_t)sr * (size_t)K + (size_t)kOff;
    boff[t] = (size_t)(tileN + row0 + 32 * t) * (size_t)K + (size_t)kOff;
  }

  floatx4 acc[4][4];
#pragma unroll
  for (int i = 0; i < 4; ++i)
#pragma unroll
    for (int j = 0; j < 4; ++j) acc[i][j] = (floatx4){0.f, 0.f, 0.f, 0.f};

  for (int k0 = 0; k0 < K; k0 += 64) {
#pragma unroll
    for (int t = 0; t < 4; ++t) {
      if (ASRC == A_F32) {
        const float* Af = (const float*)Av;
        float4 a0 = *reinterpret_cast<const float4*>(Af + aoff[t] + k0);
        float4 a1 = *reinterpret_cast<const float4*>(Af + aoff[t] + k0 + 4);
        *reinterpret_cast<short8*>(&As[(row0 + 32 * t) * 64 + kOff]) = cvt8(a0, a1);
      } else {
        const unsigned short* Au = (const unsigned short*)Av;
        *reinterpret_cast<uint4*>(&As[(row0 + 32 * t) * 64 + kOff]) =
            *reinterpret_cast<const uint4*>(&Au[aoff[t] + k0]);
      }
      float4 b0 = *reinterpret_cast<const float4*>(B + boff[t] + k0);
      float4 b1 = *reinterpret_cast<const float4*>(B + boff[t] + k0 + 4);
      *reinterpret_cast<short8*>(&Bs[(row0 + 32 * t) * 64 + kOff]) = cvt8(b0, b1);
    }
    __syncthreads();
#pragma unroll
    for (int ks = 0; ks < 2; ++ks) {
      const int kk = ks * 32 + (lane >> 4) * 8;
      short8 af[4], bfv[4];
#pragma unroll
      for (int i = 0; i < 4; ++i)
        af[i] = *reinterpret_cast<const short8*>(
            &As[(waveM * 64 + i * 16 + (lane & 15)) * 64 + kk]);
#pragma unroll
      for (int j = 0; j < 4; ++j)
        bfv[j] = *reinterpret_cast<const short8*>(
            &Bs[(waveN * 64 + j * 16 + (lane & 15)) * 64 + kk]);
#pragma unroll
      for (int i = 0; i < 4; ++i)
#pragma unroll
        for (int j = 0; j < 4; ++j)
          acc[i][j] = __builtin_amdgcn_mfma_f32_16x16x32_bf16(af[i], bfv[j], acc[i][j], 0, 0, 0);
    }
    __syncthreads();
  }

  // epilogue: C/D layout row=(lane>>4)*4+reg, col=lane&15  [m89-verified]
#pragma unroll
  for (int j = 0; j < 4; ++j) {
    const int col = tileN + waveN * 64 + j * 16 + (lane & 15);
    float bv;
    if (BIASMODE == BIAS_QKV) {
      if (col < 1024) bv = bias0[col];
      else if (col < 2048) bv = 0.f;
      else bv = bias1[col - 2048];
    } else {
      bv = bias0[col];
    }
#pragma unroll
    for (int i = 0; i < 4; ++i) {
      const int rbase = tileM + waveM * 64 + i * 16 + ((lane >> 4) * 4);
#pragma unroll
      for (int r = 0; r < 4; ++r) {
        float v = acc[i][j][r] + bv;
        if (ACT == ACT_GELU) v = 0.5f * v * (1.f + erff(v * 0.70710678118f));
        C[(size_t)(rbase + r) * (size_t)N + col] = __float2bfloat16(v);
      }
    }
  }
}

// CPB MLP: regenerate the static log-spaced coord table and run 2->512->16 MLP.
__global__ __launch_bounds__(512) void cpb_kernel(
    const float* __restrict__ w1, const float* __restrict__ b1,
    const float* __restrict__ w2, float* __restrict__ TBL)
{
  __shared__ float hid[512];
  const int i = blockIdx.x;   // 0..224
  const int j = threadIdx.x;  // 0..511
  const float d0 = ((float)(i / 15) - 7.f) / 7.f;
  const float d1 = ((float)(i % 15) - 7.f) / 7.f;
  const float t0 = copysignf(log2f(1.f + fabsf(d0)), d0);
  const float t1 = copysignf(log2f(1.f + fabsf(d1)), d1);
  float hv = t0 * w1[j * 2] + t1 * w1[j * 2 + 1] + b1[j];
  hid[j] = fmaxf(hv, 0.f);
  __syncthreads();
  if (j < 16) {
    float s = 0.f;
    for (int jj = 0; jj < 512; ++jj) s += w2[j * 512 + jj] * hid[jj];
    TBL[i * 16 + j] = 16.f / (1.f + expf(-s));
  }
}

// attention: one wave per (window, head). cosine attn + cpb bias + shift mask + softmax + PV.
__global__ __launch_bounds__(64) void attn_kernel(
    const bf16* __restrict__ QKV, const float* __restrict__ TBL,
    const float* __restrict__ ls, bf16* __restrict__ ATT)
{
  __shared__ __align__(16) float kn[64][68];
  __shared__ __align__(16) float vvs[64][68];
  __shared__ float tb[225];
  __shared__ int ids[64];

  const int bw = blockIdx.x >> 4, h = blockIdx.x & 15;
  const int t = threadIdx.x;
  const unsigned short* qkvu = (const unsigned short*)QKV;
  const size_t rb = (size_t)(bw * 64 + t) * 3072;

  float q[64];
  float s2 = 0.f;
#pragma unroll
  for (int d0 = 0; d0 < 64; d0 += 8) {
    short8 v = *reinterpret_cast<const short8*>(&qkvu[rb + h * 64 + d0]);
#pragma unroll
    for (int j = 0; j < 8; ++j) { float f = bf2f((unsigned short)v[j]); q[d0 + j] = f; s2 += f * f; }
  }
  float inv = 1.f / fmaxf(sqrtf(s2), 1e-12f);
#pragma unroll
  for (int d = 0; d < 64; ++d) q[d] *= inv;

  s2 = 0.f;
#pragma unroll
  for (int d0 = 0; d0 < 64; d0 += 8) {
    short8 v = *reinterpret_cast<const short8*>(&qkvu[rb + 1024 + h * 64 + d0]);
#pragma unroll
    for (int j = 0; j < 8; ++j) { float f = bf2f((unsigned short)v[j]); kn[t][d0 + j] = f; s2 += f * f; }
  }
  inv = 1.f / fmaxf(sqrtf(s2), 1e-12f);
#pragma unroll
  for (int d = 0; d < 64; ++d) kn[t][d] *= inv;

#pragma unroll
  for (int d0 = 0; d0 < 64; d0 += 8) {
    short8 v = *reinterpret_cast<const short8*>(&qkvu[rb + 2048 + h * 64 + d0]);
#pragma unroll
    for (int j = 0; j < 8; ++j) vvs[t][d0 + j] = bf2f((unsigned short)v[j]);
  }

  for (int i = t; i < 225; i += 64) tb[i] = TBL[i * 16 + h];

  {
    const int w2 = bw & 3, wi = w2 >> 1, wj = w2 & 1;
    const int r = t >> 3, c = t & 7;
    const int gr = wi * 8 + r, gc = wj * 8 + c;
    const int rr = (gr < 8) ? 0 : ((gr < 12) ? 1 : 2);
    const int rc = (gc < 8) ? 0 : ((gc < 12) ? 1 : 2);
    ids[t] = rr * 3 + rc;
  }
  __syncthreads();

  const float scale = expf(fminf(ls[h], 4.60517019f));
  const int rt = t >> 3, ct = t & 7;
  const int myid = ids[t];

  float sc[64];
#pragma unroll
  for (int m = 0; m < 64; ++m) {
    const floatx4* kr = reinterpret_cast<const floatx4*>(&kn[m][0]);
    float dot = 0.f;
#pragma unroll
    for (int dq = 0; dq < 16; ++dq) {
      floatx4 kv = kr[dq];
      dot += q[4 * dq + 0] * kv[0] + q[4 * dq + 1] * kv[1] +
             q[4 * dq + 2] * kv[2] + q[4 * dq + 3] * kv[3];
    }
    const int rm = m >> 3, cm = m & 7;
    const int idx = (rt - rm + 7) * 15 + (ct - cm + 7);
    float val = dot * scale + tb[idx];
    if (ids[m] != myid) val -= 100.f;
    sc[m] = val;
  }

  float mx = -1e30f;
#pragma unroll
  for (int m = 0; m < 64; ++m) mx = fmaxf(mx, sc[m]);
  float ssum = 0.f;
#pragma unroll
  for (int m = 0; m < 64; ++m) { float e = expf(sc[m] - mx); sc[m] = e; ssum += e; }
  const float rs = 1.f / ssum;

  float out[64];
#pragma unroll
  for (int d = 0; d < 64; ++d) out[d] = 0.f;
#pragma unroll
  for (int m = 0; m < 64; ++m) {
    const float p = sc[m];
    const floatx4* vr = reinterpret_cast<const floatx4*>(&vvs[m][0]);
#pragma unroll
    for (int dq = 0; dq < 16; ++dq) {
      floatx4 vv = vr[dq];
      out[4 * dq + 0] += p * vv[0];
      out[4 * dq + 1] += p * vv[1];
      out[4 * dq + 2] += p * vv[2];
      out[4 * dq + 3] += p * vv[3];
    }
  }

  unsigned short* op = (unsigned short*)ATT + (size_t)(bw * 64 + t) * 1024 + h * 64;
#pragma unroll
  for (int d0 = 0; d0 < 64; d0 += 8) {
    union { short8 v; unsigned short u[8]; } o;
#pragma unroll
    for (int j = 0; j < 8; ++j) o.u[j] = f2bf_bits(out[d0 + j] * rs);
    *reinterpret_cast<short8*>(&op[d0]) = o.v;
  }
}

// out[tok] = base[tok] + LN(src[maprow(tok)]) ; GATHER does window-reverse + roll(+4,+4).
// src bf16; base/out are f32 (xs lives in f32 d_out). base/out may alias per-token.
template <bool GATHER>
__global__ __launch_bounds__(256) void ln_residual(
    const bf16* __restrict__ src, const float* base,
    const float* __restrict__ gw, const float* __restrict__ gb,
    float* out)
{
  const int tok = blockIdx.x;
  int srow;
  if (GATHER) {
    const int bt = tok >> 8, rem = tok & 255, i = rem >> 4, j = rem & 15;
    const int p = (i + 12) & 15, qq = (j + 12) & 15;
    srow = (bt * 4 + (p >> 3) * 2 + (qq >> 3)) * 64 + (p & 7) * 8 + (qq & 7);
  } else {
    srow = tok;
  }
  const unsigned short* sp = (const unsigned short*)src + (size_t)srow * 1024;
  const int tx = threadIdx.x;
  typedef __attribute__((ext_vector_type(4))) short short4v;
  union { short4v v; unsigned short u[4]; } lv;
  lv.v = *reinterpret_cast<const short4v*>(&sp[tx * 4]);
  float v[4];
  float s = 0.f, sq = 0.f;
#pragma unroll
  for (int u = 0; u < 4; ++u) {
    float f = bf2f(lv.u[u]);
    v[u] = f; s += f; sq += f * f;
  }
#pragma unroll
  for (int off = 32; off > 0; off >>= 1) { s += __shfl_xor(s, off); sq += __shfl_xor(sq, off); }
  __shared__ float rs_[4], rq_[4];
  if ((tx & 63) == 0) { rs_[tx >> 6] = s; rq_[tx >> 6] = sq; }
  __syncthreads();
  s = rs_[0] + rs_[1] + rs_[2] + rs_[3];
  sq = rq_[0] + rq_[1] + rq_[2] + rq_[3];
  const float mean = s * (1.f / 1024.f);
  const float var = sq * (1.f / 1024.f) - mean * mean;
  const float rstd = rsqrtf(var + 1e-5f);

  const float* bp = base + (size_t)tok * 1024;
  float4 b4 = *reinterpret_cast<const float4*>(&bp[tx * 4]);
  float bl[4] = {b4.x, b4.y, b4.z, b4.w};
  float4 o4;
  float* ol = (float*)&o4;
#pragma unroll
  for (int u = 0; u < 4; ++u) {
    const int c = tx * 4 + u;
    ol[u] = bl[u] + (v[u] - mean) * rstd * gw[c] + gb[c];
  }
  float* op = out + (size_t)tok * 1024;
  *reinterpret_cast<float4*>(&op[tx * 4]) = o4;
}

extern "C" void kernel_launch(void* const* d_in, const int* in_sizes, int n_in,
                              void* d_out, int out_size, void* d_ws, size_t ws_size,
                              hipStream_t stream) {
  (void)in_sizes; (void)n_in; (void)out_size; (void)ws_size;
  const float* x      = (const float*)d_in[0];
  const float* qkv_w  = (const float*)d_in[1];
  const float* q_bias = (const float*)d_in[2];
  const float* v_bias = (const float*)d_in[3];
  const float* lscale = (const float*)d_in[4];
  const float* cpb_w1 = (const float*)d_in[5];
  const float* cpb_b1 = (const float*)d_in[6];
  const float* cpb_w2 = (const float*)d_in[7];
  const float* proj_w = (const float*)d_in[8];
  const float* proj_b = (const float*)d_in[9];
  const float* n1w    = (const float*)d_in[10];
  const float* n1b    = (const float*)d_in[11];
  const float* fc1_w  = (const float*)d_in[12];
  const float* fc1_b  = (const float*)d_in[13];
  const float* fc2_w  = (const float*)d_in[14];
  const float* fc2_b  = (const float*)d_in[15];
  const float* n2w    = (const float*)d_in[16];
  const float* n2b    = (const float*)d_in[17];
  float* out = (float*)d_out;   // reference output dtype is float32

  // Chunked over 4 groups of 8192 tokens (32 images, window-aligned).
  // Peak workspace: 100.7 MB.
  char* ws = (char*)d_ws;
  bf16*  QKV = (bf16*)(ws);                    // [8192,3072] bf16 = 50.3 MB (region A)
  bf16*  H   = (bf16*)(ws);                    // [8192,4096] bf16 = 67.1 MB (region A, QKV dead)
  bf16*  ATT = (bf16*)(ws + 67108864);         // [8192,1024] bf16 = 16.8 MB (region B)
  bf16*  F2  = (bf16*)(ws + 67108864);         // reuse region B (ATT dead after proj)
  bf16*  PROJ= (bf16*)(ws + 83886080);         // [8192,1024] bf16 = 16.8 MB (region C)
  float* TBL = (float*)(ws + 100663296);       // [225,16] f32 = 14.4 KB

  cpb_kernel<<<225, 512, 0, stream>>>(cpb_w1, cpb_b1, cpb_w2, TBL);

  for (int ch = 0; ch < 4; ++ch) {
    const size_t tokBase = (size_t)ch * 8192;
    const float* x_c = x + tokBase * 1024;
    float* out_c = out + tokBase * 1024;

    // QKV with fused shift+window gather (chunk-local rows; images self-contained)
    gemm_bt<A_F32, 1, BIAS_QKV, ACT_NONE><<<dim3(64, 24), 256, 0, stream>>>(
        x_c, qkv_w, q_bias, v_bias, QKV, 8192, 3072, 1024);
    // 128 windows x 16 heads
    attn_kernel<<<2048, 64, 0, stream>>>(QKV, TBL, lscale, ATT);
    gemm_bt<A_BF16, 0, BIAS_SIMPLE, ACT_NONE><<<dim3(64, 8), 256, 0, stream>>>(
        ATT, proj_w, proj_b, nullptr, PROJ, 8192, 1024, 1024);
    // window-reverse + roll + LN + residual; xs chunk lives in d_out (f32)
    ln_residual<true><<<8192, 256, 0, stream>>>(PROJ, x_c, n1w, n1b, out_c);
    // MLP (fc1 reads f32 xs from d_out)
    gemm_bt<A_F32, 0, BIAS_SIMPLE, ACT_GELU><<<dim3(64, 32), 256, 0, stream>>>(
        out_c, fc1_w, fc1_b, nullptr, H, 8192, 4096, 1024);
    gemm_bt<A_BF16, 0, BIAS_SIMPLE, ACT_NONE><<<dim3(64, 8), 256, 0, stream>>>(
        H, fc2_w, fc2_b, nullptr, F2, 8192, 1024, 4096);
    ln_residual<false><<<8192, 256, 0, stream>>>(F2, out_c, n2w, n2b, out_c);
  }
}